// Round 14
// baseline (300.321 us; speedup 1.0000x reference)
//
#include <hip/hip_runtime.h>
#include <math.h>

#define N_NODES 50000
#define N_EDGES 500000
#define IN_CH 256
#define D1 512          // HEADS*HID
#define HEADS 8
#define HID 64
#define OUT_CH 16
#define NEG_SLOPE 0.2f

typedef __bf16 bf16x8 __attribute__((ext_vector_type(8)));
typedef float f32x4 __attribute__((ext_vector_type(4)));
typedef float f32x2 __attribute__((ext_vector_type(2)));

// convert 8 packed fp8 e4m3 (uint2) -> 8 floats via HW v_cvt_pk_f32_fp8
__device__ inline void fp8x8_to_f32(uint2 u, float* f) {
    f32x2 p0 = __builtin_amdgcn_cvt_pk_f32_fp8(u.x, false);
    f32x2 p1 = __builtin_amdgcn_cvt_pk_f32_fp8(u.x, true);
    f32x2 p2 = __builtin_amdgcn_cvt_pk_f32_fp8(u.y, false);
    f32x2 p3 = __builtin_amdgcn_cvt_pk_f32_fp8(u.y, true);
    f[0] = p0.x; f[1] = p0.y; f[2] = p1.x; f[3] = p1.y;
    f[4] = p2.x; f[5] = p2.y; f[6] = p3.x; f[7] = p3.y;
}

__device__ inline void fp8x16_to_f32(uint4 u, float* f) {
    fp8x8_to_f32(make_uint2(u.x, u.y), f);
    fp8x8_to_f32(make_uint2(u.z, u.w), f + 8);
}

__device__ inline unsigned char f32_to_fp8(float v) {
    return (unsigned char)(__builtin_amdgcn_cvt_pk_fp8_f32(v, v, 0, false) & 0xff);
}

// async global->LDS, 16B per lane; LDS dest = wave-uniform base + lane*16
__device__ inline void gl_lds16(const __bf16* g, __bf16* l) {
    __builtin_amdgcn_global_load_lds(
        (const __attribute__((address_space(1))) unsigned int*)g,
        (__attribute__((address_space(3))) unsigned int*)l,
        16, 0, 0);
}

// ---------------- prep: X/W converts + edge histogram (deg pre-zeroed) ------
__global__ __launch_bounds__(256) void k_prep(const float* __restrict__ X,
                                              const float* __restrict__ W1,
                                              const float* __restrict__ W2,
                                              const int* __restrict__ edst,
                                              __bf16* __restrict__ Xb,
                                              __bf16* __restrict__ Wt,
                                              __bf16* __restrict__ Wt2,
                                              int* __restrict__ deg) {
    int t = blockIdx.x * 256 + threadIdx.x;
    int nthr = gridDim.x * 256;
    for (int i = t; i < N_NODES * IN_CH / 8; i += nthr) {
        size_t base = (size_t)i * 8;
        float4 v0 = *(const float4*)&X[base];
        float4 v1 = *(const float4*)&X[base + 4];
        __bf16 o[8] = {(__bf16)v0.x, (__bf16)v0.y, (__bf16)v0.z, (__bf16)v0.w,
                       (__bf16)v1.x, (__bf16)v1.y, (__bf16)v1.z, (__bf16)v1.w};
        *(uint4*)&Xb[base] = *(uint4*)o;
    }
    for (int i = t; i < D1 * IN_CH; i += nthr) {
        int n = i >> 8, k = i & 255;
        Wt[i] = (__bf16)W1[k * D1 + n];
    }
    for (int i = t; i < D1 * OUT_CH; i += nthr) {
        int n = i >> 9, k = i & 511;
        Wt2[i] = (__bf16)W2[k * OUT_CH + n];
    }
    for (int i = t; i < N_EDGES; i += nthr) atomicAdd(&deg[edst[i]], 1);
}

// ---------------- GEMM1 (MFMA, global_load_lds staging) + att1, fp8 H out ---
__global__ __launch_bounds__(256) void k_gemm1_mfma(const __bf16* __restrict__ Xb,
                                                    const __bf16* __restrict__ Wt,
                                                    const float* __restrict__ att_src,
                                                    const float* __restrict__ att_dst,
                                                    unsigned char* __restrict__ Hf8,
                                                    float* __restrict__ a_src1,
                                                    float* __restrict__ a_dst1) {
    __shared__ __align__(16) __bf16 As[128 * 32];   // unpadded: stride 32
    __shared__ __align__(16) __bf16 Bs[128 * 32];
    int tid = threadIdx.x;
    int wid = tid >> 6, lane = tid & 63;
    int wr = wid >> 1, wc = wid & 1;           // 2x2 waves of 64x64
    int row0 = blockIdx.x * 128;
    int col0 = blockIdx.y * 128;
    int lq = lane >> 4;
    int lm = lane & 15;
    f32x4 acc[4][4] = {};
    for (int kt = 0; kt < IN_CH / 32; ++kt) {
        int k0 = kt * 32;
        #pragma unroll
        for (int it = 0; it < 2; ++it) {
            int idx = tid + it * 256;          // 0..511
            int r  = idx >> 2;
            int c8 = (idx & 3) * 8;
            gl_lds16(&Xb[(size_t)(row0 + r) * IN_CH + k0 + c8], &As[idx * 8]);
            gl_lds16(&Wt[(size_t)(col0 + r) * IN_CH + k0 + c8], &Bs[idx * 8]);
        }
        __syncthreads();   // drains vmcnt: tile visible
        bf16x8 af[4], bfr[4];
        #pragma unroll
        for (int i = 0; i < 4; ++i) af[i]  = *(bf16x8*)&As[(wr * 64 + i * 16 + lm) * 32 + lq * 8];
        #pragma unroll
        for (int j = 0; j < 4; ++j) bfr[j] = *(bf16x8*)&Bs[(wc * 64 + j * 16 + lm) * 32 + lq * 8];
        #pragma unroll
        for (int i = 0; i < 4; ++i)
            #pragma unroll
            for (int j = 0; j < 4; ++j)
                acc[i][j] = __builtin_amdgcn_mfma_f32_16x16x32_bf16(af[i], bfr[j], acc[i][j], 0, 0, 0);
        __syncthreads();   // all reads done before next overwrite
    }
    // ---- epilogue: fused att logits + fp8 byte stores ----
    int head = blockIdx.y * 2 + wc;
    float as_v[4], ad_v[4];
    #pragma unroll
    for (int j = 0; j < 4; ++j) {
        as_v[j] = att_src[head * HID + j * 16 + lm];
        ad_v[j] = att_dst[head * HID + j * 16 + lm];
    }
    #pragma unroll
    for (int i = 0; i < 4; ++i) {
        int rbase = row0 + wr * 64 + i * 16 + lq * 4;
        #pragma unroll
        for (int r = 0; r < 4; ++r) {
            int grow = rbase + r;
            float ps = 0.f, pd = 0.f;
            #pragma unroll
            for (int j = 0; j < 4; ++j) {
                float v = acc[i][j][r];
                ps += v * as_v[j];
                pd += v * ad_v[j];
                if (grow < N_NODES)
                    Hf8[(size_t)grow * D1 + col0 + wc * 64 + j * 16 + lm] = f32_to_fp8(v);
            }
            #pragma unroll
            for (int off = 1; off < 16; off <<= 1) {
                ps += __shfl_xor(ps, off);
                pd += __shfl_xor(pd, off);
            }
            if (lm == 0 && grow < N_NODES) {
                a_src1[grow * HEADS + head] = ps;
                a_dst1[grow * HEADS + head] = pd;
            }
        }
    }
}

// ---------------- CSR scan phase 1 ------------------------------------------
__global__ __launch_bounds__(1024) void k_scan1(const int* __restrict__ deg,
                                                int* __restrict__ offsets,
                                                int* __restrict__ bsum) {
    __shared__ int wsum[16];
    int tid = threadIdx.x, lane = tid & 63, wid = tid >> 6;
    int i = blockIdx.x * 1024 + tid;
    int v = (i < N_NODES) ? deg[i] : 0;
    int x = v;
    #pragma unroll
    for (int off = 1; off < 64; off <<= 1) {
        int t = __shfl_up(x, off);
        if (lane >= off) x += t;
    }
    if (lane == 63) wsum[wid] = x;
    __syncthreads();
    if (wid == 0) {
        int s = (lane < 16) ? wsum[lane] : 0;
        #pragma unroll
        for (int off = 1; off < 16; off <<= 1) {
            int t = __shfl_up(s, off);
            if (lane >= off) s += t;
        }
        if (lane < 16) wsum[lane] = s;
    }
    __syncthreads();
    int wbase = wid ? wsum[wid - 1] : 0;
    if (i < N_NODES) offsets[i] = wbase + x - v;
    if (tid == 1023) bsum[blockIdx.x] = wsum[15];
}

// ---------------- scan phase 2+3 fused ---------------------------------------
__global__ __launch_bounds__(256) void k_scan3(int* __restrict__ offsets,
                                               const int* __restrict__ bsum,
                                               int* __restrict__ cursor) {
    __shared__ int bpre_s[64];
    int tid = threadIdx.x;
    const int nb = (N_NODES + 1023) / 1024;   // 49
    if (tid < 64) {
        int v = (tid < nb) ? bsum[tid] : 0;
        int x = v;
        #pragma unroll
        for (int off = 1; off < 64; off <<= 1) {
            int t = __shfl_up(x, off);
            if (tid >= off) x += t;
        }
        bpre_s[tid] = x - v;
        if (blockIdx.x == 0 && tid == nb - 1) offsets[N_NODES] = x;
    }
    __syncthreads();
    int i = blockIdx.x * 256 + tid;
    if (i < N_NODES) {
        int o = offsets[i] + bpre_s[i >> 10];
        offsets[i] = o;
        cursor[i] = o;
    }
}

// ---------------- scatter + fused layer-1 edge weights ----------------------
__global__ void k_scatter(const int* __restrict__ esrc, const int* __restrict__ edst,
                          const float* __restrict__ a_src, const float* __restrict__ a_dst,
                          int* __restrict__ cursor, int* __restrict__ csr,
                          float* __restrict__ w1) {
    int e = blockIdx.x * blockDim.x + threadIdx.x;
    if (e >= N_EDGES) return;
    int s = esrc[e], d = edst[e];
    int pos = atomicAdd(&cursor[d], 1);
    csr[pos] = s;
    float4 s0 = *(const float4*)&a_src[s * HEADS];
    float4 s1 = *(const float4*)&a_src[s * HEADS + 4];
    float4 d0 = *(const float4*)&a_dst[d * HEADS];
    float4 d1 = *(const float4*)&a_dst[d * HEADS + 4];
    float ev[8] = {s0.x + d0.x, s0.y + d0.y, s0.z + d0.z, s0.w + d0.w,
                   s1.x + d1.x, s1.y + d1.y, s1.z + d1.z, s1.w + d1.w};
    float w[8];
    #pragma unroll
    for (int h = 0; h < 8; ++h) {
        float v = ev[h] > 0.f ? ev[h] : NEG_SLOPE * ev[h];
        w[h] = __expf(v);
    }
    *(float4*)&w1[(size_t)pos * 8]     = make_float4(w[0], w[1], w[2], w[3]);
    *(float4*)&w1[(size_t)pos * 8 + 4] = make_float4(w[4], w[5], w[6], w[7]);
}

// ---------------- layer-1 aggregation: pair-edge 1KB gathers, 4-deep MLP ----
// One wave per node; 16 ch/lane over 32 lanes; lanes 0-31 even pair-edge,
// 32-63 odd, same uint4 gather. Main loop keeps 4 gathers (8 edges) in
// flight; convert+accumulate per gather to bound VGPR (<64).
__global__ __launch_bounds__(256) void k_agg1(const unsigned char* __restrict__ Hf8,
                                              const float* __restrict__ a_src,
                                              const float* __restrict__ a_dst,
                                              const float* __restrict__ w1,
                                              const int* __restrict__ offsets,
                                              const int* __restrict__ csr,
                                              const float* __restrict__ b1,
                                              __bf16* __restrict__ OUT) {
    int wave = (blockIdx.x * blockDim.x + threadIdx.x) >> 6;
    int lane = threadIdx.x & 63;
    if (wave >= N_NODES) return;
    int d = wave;
    int half = lane >> 5;      // edge parity this lane handles
    int l32 = lane & 31;
    int chb = l32 * 16;        // 16 channels per lane
    int head = l32 >> 2;
    float o[16];
    #pragma unroll
    for (int j = 0; j < 16; ++j) o[j] = 0.f;
    float lsum = 0.f;
    if (half == 0) {           // self-loop handled once
        float es = a_src[d * HEADS + head] + a_dst[d * HEADS + head];
        es = es > 0.f ? es : NEG_SLOPE * es;
        float wself = __expf(es);
        uint4 hu = *(const uint4*)&Hf8[(size_t)d * D1 + chb];
        float hv[16];
        fp8x16_to_f32(hu, hv);
        lsum = wself;
        #pragma unroll
        for (int j = 0; j < 16; ++j) o[j] = wself * hv[j];
    }
    int beg = offsets[d], end = offsets[d + 1];
    int idx = beg;
    for (; idx + 8 <= end; idx += 8) {       // 8 edges / iter, 4 gathers in flight
        int e0 = idx + half, e1 = idx + 2 + half, e2 = idx + 4 + half, e3 = idx + 6 + half;
        int s0 = csr[e0], s1 = csr[e1], s2 = csr[e2], s3 = csr[e3];
        uint4 u0 = *(const uint4*)&Hf8[(size_t)s0 * D1 + chb];
        uint4 u1 = *(const uint4*)&Hf8[(size_t)s1 * D1 + chb];
        uint4 u2 = *(const uint4*)&Hf8[(size_t)s2 * D1 + chb];
        uint4 u3 = *(const uint4*)&Hf8[(size_t)s3 * D1 + chb];
        float w0 = w1[(size_t)e0 * 8 + head];
        float w1v = w1[(size_t)e1 * 8 + head];
        float w2 = w1[(size_t)e2 * 8 + head];
        float w3 = w1[(size_t)e3 * 8 + head];
        lsum += (w0 + w1v) + (w2 + w3);
        float f[16];
        fp8x16_to_f32(u0, f);
        #pragma unroll
        for (int j = 0; j < 16; ++j) o[j] += w0 * f[j];
        fp8x16_to_f32(u1, f);
        #pragma unroll
        for (int j = 0; j < 16; ++j) o[j] += w1v * f[j];
        fp8x16_to_f32(u2, f);
        #pragma unroll
        for (int j = 0; j < 16; ++j) o[j] += w2 * f[j];
        fp8x16_to_f32(u3, f);
        #pragma unroll
        for (int j = 0; j < 16; ++j) o[j] += w3 * f[j];
    }
    for (; idx + 4 <= end; idx += 4) {       // 4 edges, 2 gathers
        int eA = idx + half, eB = idx + 2 + half;
        int sA = csr[eA], sB = csr[eB];
        uint4 uA = *(const uint4*)&Hf8[(size_t)sA * D1 + chb];
        uint4 uB = *(const uint4*)&Hf8[(size_t)sB * D1 + chb];
        float wA = w1[(size_t)eA * 8 + head];
        float wB = w1[(size_t)eB * 8 + head];
        lsum += wA + wB;
        float f[16];
        fp8x16_to_f32(uA, f);
        #pragma unroll
        for (int j = 0; j < 16; ++j) o[j] += wA * f[j];
        fp8x16_to_f32(uB, f);
        #pragma unroll
        for (int j = 0; j < 16; ++j) o[j] += wB * f[j];
    }
    for (; idx < end; idx += 2) {            // tail (validity-masked)
        int e = idx + half;
        bool valid = e < end;
        int s = valid ? csr[e] : csr[idx];
        float w = valid ? w1[(size_t)e * 8 + head] : 0.f;
        uint4 u = *(const uint4*)&Hf8[(size_t)s * D1 + chb];
        float f[16];
        fp8x16_to_f32(u, f);
        lsum += w;
        #pragma unroll
        for (int j = 0; j < 16; ++j) o[j] += w * f[j];
    }
    // combine edge-parity halves
    #pragma unroll
    for (int j = 0; j < 16; ++j) o[j] += __shfl_xor(o[j], 32);
    lsum += __shfl_xor(lsum, 32);
    if (half == 0) {
        float inv = 1.0f / (lsum + 1e-16f);
        __bf16 r[16];
        #pragma unroll
        for (int j = 0; j < 16; ++j) {
            float v = o[j] * inv + b1[chb + j];
            v = v > 0.f ? v : (__expf(v) - 1.0f);   // ELU (cheap form)
            r[j] = (__bf16)v;
        }
        *(uint4*)&OUT[(size_t)d * D1 + chb]     = *(uint4*)&r[0];
        *(uint4*)&OUT[(size_t)d * D1 + chb + 8] = *(uint4*)&r[8];
    }
}

// ---------------- GEMM2 (MFMA, no LDS) + layer-2 logits, bf16 H2 ------------
__global__ __launch_bounds__(256) void k_gemm2_mfma(const __bf16* __restrict__ A,
                                                    const __bf16* __restrict__ Wt2,
                                                    const float* __restrict__ as2v,
                                                    const float* __restrict__ ad2v,
                                                    __bf16* __restrict__ H2,
                                                    float* __restrict__ a_src2,
                                                    float* __restrict__ a_dst2) {
    int tid = threadIdx.x;
    int wid = tid >> 6, lane = tid & 63;
    int lq = lane >> 4, lm = lane & 15;
    int row0 = blockIdx.x * 64 + wid * 16;
    int arow = row0 + lm;
    const __bf16* ap = A + (size_t)(arow < N_NODES ? arow : 0) * D1;
    f32x4 acc = {};
    #pragma unroll
    for (int k0 = 0; k0 < 16; ++k0) {
        bf16x8 af  = *(const bf16x8*)&ap[k0 * 32 + lq * 8];
        bf16x8 bfr = *(const bf16x8*)&Wt2[lm * D1 + k0 * 32 + lq * 8];
        acc = __builtin_amdgcn_mfma_f32_16x16x32_bf16(af, bfr, acc, 0, 0, 0);
    }
    float as_c = as2v[lm], ad_c = ad2v[lm];
    #pragma unroll
    for (int r = 0; r < 4; ++r) {
        int gr = row0 + lq * 4 + r;
        float v = acc[r];
        if (gr < N_NODES) H2[gr * OUT_CH + lm] = (__bf16)v;
        float ps = v * as_c, pd = v * ad_c;
        #pragma unroll
        for (int off = 1; off < 16; off <<= 1) {
            ps += __shfl_xor(ps, off);
            pd += __shfl_xor(pd, off);
        }
        if (lm == 0 && gr < N_NODES) { a_src2[gr] = ps; a_dst2[gr] = pd; }
    }
}

// ---------------- layer-2 aggregation + inline weights + log_softmax --------
__global__ __launch_bounds__(256) void k_agg2(const __bf16* __restrict__ H2,
                                              const float* __restrict__ a_src,
                                              const float* __restrict__ a_dst,
                                              const int* __restrict__ offsets,
                                              const int* __restrict__ csr,
                                              const float* __restrict__ b2,
                                              float* __restrict__ OUT) {
    int wave = (blockIdx.x * blockDim.x + threadIdx.x) >> 6;
    int lane = threadIdx.x & 63;
    if (wave >= N_NODES) return;
    int d = wave;
    int g = lane >> 4, c = lane & 15;
    float ad = a_dst[d];
    float es = a_src[d] + ad;
    es = es > 0.f ? es : NEG_SLOPE * es;
    float wself = __expf(es);
    int beg = offsets[d], end = offsets[d + 1];
    float o = 0.f, lsum = 0.f;
    if (g == 0) {
        o = wself * (float)H2[d * OUT_CH + c];
        lsum = wself;
    }
    for (int idx = beg + g; idx < end; idx += 4) {
        int s = csr[idx];
        float e = a_src[s] + ad;
        e = e > 0.f ? e : NEG_SLOPE * e;
        float w = __expf(e);
        lsum += w;
        o += w * (float)H2[s * OUT_CH + c];
    }
    o += __shfl_xor(o, 16);  o += __shfl_xor(o, 32);
    lsum += __shfl_xor(lsum, 16);  lsum += __shfl_xor(lsum, 32);
    float v = o / (lsum + 1e-16f) + b2[c];
    float mx = v;
    #pragma unroll
    for (int off = 1; off < 16; off <<= 1) mx = fmaxf(mx, __shfl_xor(mx, off));
    float se = __expf(v - mx);
    #pragma unroll
    for (int off = 1; off < 16; off <<= 1) se += __shfl_xor(se, off);
    float res = v - mx - logf(se);
    if (lane < 16) OUT[d * OUT_CH + lane] = res;
}

// ---------------- launcher --------------------------------------------------
extern "C" void kernel_launch(void* const* d_in, const int* in_sizes, int n_in,
                              void* d_out, int out_size, void* d_ws, size_t ws_size,
                              hipStream_t stream) {
    const float* x        = (const float*)d_in[0];
    const int*   ei       = (const int*)d_in[1];
    const float* W1       = (const float*)d_in[2];
    const float* att_src1 = (const float*)d_in[3];
    const float* att_dst1 = (const float*)d_in[4];
    const float* b1       = (const float*)d_in[5];
    const float* W2       = (const float*)d_in[6];
    const float* att_src2 = (const float*)d_in[7];
    const float* att_dst2 = (const float*)d_in[8];
    const float* b2       = (const float*)d_in[9];
    float* out = (float*)d_out;

    const int* esrc = ei;
    const int* edst = ei + N_EDGES;

    char* ws = (char*)d_ws;
    size_t off = 0;
    auto alloc = [&](size_t bytes) { char* p = ws + off; off = (off + bytes + 255) & ~(size_t)255; return p; };
    unsigned char* Hf8 = (unsigned char*)alloc((size_t)N_NODES * D1); // 25.6 MB
    __bf16* out1   = (__bf16*)alloc((size_t)N_NODES * D1 * 2);        // 51.2 MB
    __bf16* Xb     = (__bf16*)alloc((size_t)N_NODES * IN_CH * 2);     // 25.6 MB
    __bf16* Wt     = (__bf16*)alloc((size_t)D1 * IN_CH * 2);          // (also absorbs gemm1 overread)
    __bf16* Wt2    = (__bf16*)alloc((size_t)D1 * OUT_CH * 2);
    float* a_src1  = (float*)alloc((size_t)N_NODES * HEADS * 4);
    float* a_dst1  = (float*)alloc((size_t)N_NODES * HEADS * 4);
    float* w1      = (float*)alloc((size_t)N_EDGES * HEADS * 4);      // 16 MB
    __bf16* h2     = (__bf16*)alloc((size_t)N_NODES * OUT_CH * 2);    // 1.6 MB
    float* a_src2  = (float*)alloc((size_t)N_NODES * 4);
    float* a_dst2  = (float*)alloc((size_t)N_NODES * 4);
    int*   deg     = (int*)alloc((size_t)N_NODES * 4);
    int*   offsets = (int*)alloc((size_t)(N_NODES + 1) * 4);
    int*   cursor  = (int*)alloc((size_t)N_NODES * 4);
    int*   csr     = (int*)alloc((size_t)N_EDGES * 4);
    int*   bsum    = (int*)alloc(64 * 4);
    (void)ws_size;

    // 0. zero deg, then prep (X/W converts + histogram)
    hipMemsetAsync(deg, 0, (size_t)N_NODES * 4, stream);
    k_prep<<<512, 256, 0, stream>>>(x, W1, W2, edst, Xb, Wt, Wt2, deg);
    // 1. GEMM1 (MFMA, async LDS staging) + att1 logits, fp8 H out
    dim3 g1((N_NODES + 127) / 128, D1 / 128);
    k_gemm1_mfma<<<g1, 256, 0, stream>>>(Xb, Wt, att_src1, att_dst1, Hf8, a_src1, a_dst1);
    // 2. CSR build
    int nb = (N_NODES + 1023) / 1024;
    k_scan1<<<nb, 1024, 0, stream>>>(deg, offsets, bsum);
    k_scan3<<<(N_NODES + 255) / 256, 256, 0, stream>>>(offsets, bsum, cursor);
    k_scatter<<<(N_EDGES + 255) / 256, 256, 0, stream>>>(esrc, edst, a_src1, a_dst1,
                                                         cursor, csr, w1);
    // 3. layer-1 aggregation (+bias+ELU), pair-edge fp8 gather, 4-deep MLP
    k_agg1<<<(N_NODES * 64 + 255) / 256, 256, 0, stream>>>(Hf8, a_src1, a_dst1, w1, offsets, csr, b1, out1);
    // 4. GEMM2 (MFMA) + layer-2 logits, bf16 H2
    k_gemm2_mfma<<<(N_NODES + 63) / 64, 256, 0, stream>>>(out1, Wt2, att_src2, att_dst2, h2, a_src2, a_dst2);
    // 5. layer-2 aggregation (inline weights) + log_softmax
    k_agg2<<<(N_NODES * 64 + 255) / 256, 256, 0, stream>>>(h2, a_src2, a_dst2, offsets, csr, b2, out);
}

// Round 15
// 293.655 us; speedup vs baseline: 1.0227x; 1.0227x over previous
//
#include <hip/hip_runtime.h>
#include <math.h>

#define N_NODES 50000
#define N_EDGES 500000
#define IN_CH 256
#define D1 512          // HEADS*HID
#define HEADS 8
#define HID 64
#define OUT_CH 16
#define NEG_SLOPE 0.2f

typedef __bf16 bf16x8 __attribute__((ext_vector_type(8)));
typedef float f32x4 __attribute__((ext_vector_type(4)));
typedef float f32x2 __attribute__((ext_vector_type(2)));

// convert 8 packed fp8 e4m3 (uint2) -> 8 floats via HW v_cvt_pk_f32_fp8
__device__ inline void fp8x8_to_f32(uint2 u, float* f) {
    f32x2 p0 = __builtin_amdgcn_cvt_pk_f32_fp8(u.x, false);
    f32x2 p1 = __builtin_amdgcn_cvt_pk_f32_fp8(u.x, true);
    f32x2 p2 = __builtin_amdgcn_cvt_pk_f32_fp8(u.y, false);
    f32x2 p3 = __builtin_amdgcn_cvt_pk_f32_fp8(u.y, true);
    f[0] = p0.x; f[1] = p0.y; f[2] = p1.x; f[3] = p1.y;
    f[4] = p2.x; f[5] = p2.y; f[6] = p3.x; f[7] = p3.y;
}

__device__ inline void fp8x16_to_f32(uint4 u, float* f) {
    fp8x8_to_f32(make_uint2(u.x, u.y), f);
    fp8x8_to_f32(make_uint2(u.z, u.w), f + 8);
}

__device__ inline unsigned char f32_to_fp8(float v) {
    return (unsigned char)(__builtin_amdgcn_cvt_pk_fp8_f32(v, v, 0, false) & 0xff);
}

// async global->LDS, 16B per lane; LDS dest = wave-uniform base + lane*16
__device__ inline void gl_lds16(const __bf16* g, __bf16* l) {
    __builtin_amdgcn_global_load_lds(
        (const __attribute__((address_space(1))) unsigned int*)g,
        (__attribute__((address_space(3))) unsigned int*)l,
        16, 0, 0);
}

// ---------------- prep: X/W converts + edge histogram (deg pre-zeroed) ------
__global__ __launch_bounds__(256) void k_prep(const float* __restrict__ X,
                                              const float* __restrict__ W1,
                                              const float* __restrict__ W2,
                                              const int* __restrict__ edst,
                                              __bf16* __restrict__ Xb,
                                              __bf16* __restrict__ Wt,
                                              __bf16* __restrict__ Wt2,
                                              int* __restrict__ deg) {
    int t = blockIdx.x * 256 + threadIdx.x;
    int nthr = gridDim.x * 256;
    for (int i = t; i < N_NODES * IN_CH / 8; i += nthr) {
        size_t base = (size_t)i * 8;
        float4 v0 = *(const float4*)&X[base];
        float4 v1 = *(const float4*)&X[base + 4];
        __bf16 o[8] = {(__bf16)v0.x, (__bf16)v0.y, (__bf16)v0.z, (__bf16)v0.w,
                       (__bf16)v1.x, (__bf16)v1.y, (__bf16)v1.z, (__bf16)v1.w};
        *(uint4*)&Xb[base] = *(uint4*)o;
    }
    for (int i = t; i < D1 * IN_CH; i += nthr) {
        int n = i >> 8, k = i & 255;
        Wt[i] = (__bf16)W1[k * D1 + n];
    }
    for (int i = t; i < D1 * OUT_CH; i += nthr) {
        int n = i >> 9, k = i & 511;
        Wt2[i] = (__bf16)W2[k * OUT_CH + n];
    }
    for (int i = t; i < N_EDGES; i += nthr) atomicAdd(&deg[edst[i]], 1);
}

// ---------------- GEMM1 (MFMA, dbuf global_load_lds) + att1, fp8 H out ------
// Double-buffered async staging: tile kt+1 streams into buf[1-cur] while
// MFMAs consume buf[cur]; ONE barrier per K-iteration (drains vmcnt after a
// full compute phase instead of before it).
__global__ __launch_bounds__(256) void k_gemm1_mfma(const __bf16* __restrict__ Xb,
                                                    const __bf16* __restrict__ Wt,
                                                    const float* __restrict__ att_src,
                                                    const float* __restrict__ att_dst,
                                                    unsigned char* __restrict__ Hf8,
                                                    float* __restrict__ a_src1,
                                                    float* __restrict__ a_dst1) {
    __shared__ __align__(16) __bf16 As[2][128 * 32];   // unpadded: stride 32
    __shared__ __align__(16) __bf16 Bs[2][128 * 32];
    int tid = threadIdx.x;
    int wid = tid >> 6, lane = tid & 63;
    int wr = wid >> 1, wc = wid & 1;           // 2x2 waves of 64x64
    int row0 = blockIdx.x * 128;
    int col0 = blockIdx.y * 128;
    int lq = lane >> 4;
    int lm = lane & 15;
    // per-thread staging coordinates (2 chunks each)
    int r_st[2], c_st[2], off_st[2];
    #pragma unroll
    for (int it = 0; it < 2; ++it) {
        int idx = tid + it * 256;              // 0..511
        r_st[it] = idx >> 2;
        c_st[it] = (idx & 3) * 8;
        off_st[it] = idx * 8;
    }
    f32x4 acc[4][4] = {};
    // preload tile 0 into buf 0
    #pragma unroll
    for (int it = 0; it < 2; ++it) {
        gl_lds16(&Xb[(size_t)(row0 + r_st[it]) * IN_CH + c_st[it]], &As[0][off_st[it]]);
        gl_lds16(&Wt[(size_t)(col0 + r_st[it]) * IN_CH + c_st[it]], &Bs[0][off_st[it]]);
    }
    __syncthreads();   // tile 0 ready
    for (int kt = 0; kt < IN_CH / 32; ++kt) {
        int cur = kt & 1;
        // issue async stage of tile kt+1 into the other buffer (overlaps MFMA)
        if (kt + 1 < IN_CH / 32) {
            int k0 = (kt + 1) * 32;
            int nxt = 1 - cur;
            #pragma unroll
            for (int it = 0; it < 2; ++it) {
                gl_lds16(&Xb[(size_t)(row0 + r_st[it]) * IN_CH + k0 + c_st[it]], &As[nxt][off_st[it]]);
                gl_lds16(&Wt[(size_t)(col0 + r_st[it]) * IN_CH + k0 + c_st[it]], &Bs[nxt][off_st[it]]);
            }
        }
        // compute on current buffer
        bf16x8 af[4], bfr[4];
        #pragma unroll
        for (int i = 0; i < 4; ++i) af[i]  = *(bf16x8*)&As[cur][(wr * 64 + i * 16 + lm) * 32 + lq * 8];
        #pragma unroll
        for (int j = 0; j < 4; ++j) bfr[j] = *(bf16x8*)&Bs[cur][(wc * 64 + j * 16 + lm) * 32 + lq * 8];
        #pragma unroll
        for (int i = 0; i < 4; ++i)
            #pragma unroll
            for (int j = 0; j < 4; ++j)
                acc[i][j] = __builtin_amdgcn_mfma_f32_16x16x32_bf16(af[i], bfr[j], acc[i][j], 0, 0, 0);
        __syncthreads();   // drains vmcnt: tile kt+1 ready; reads of buf[cur] done
    }
    // ---- epilogue: fused att logits + fp8 byte stores ----
    int head = blockIdx.y * 2 + wc;
    float as_v[4], ad_v[4];
    #pragma unroll
    for (int j = 0; j < 4; ++j) {
        as_v[j] = att_src[head * HID + j * 16 + lm];
        ad_v[j] = att_dst[head * HID + j * 16 + lm];
    }
    #pragma unroll
    for (int i = 0; i < 4; ++i) {
        int rbase = row0 + wr * 64 + i * 16 + lq * 4;
        #pragma unroll
        for (int r = 0; r < 4; ++r) {
            int grow = rbase + r;
            float ps = 0.f, pd = 0.f;
            #pragma unroll
            for (int j = 0; j < 4; ++j) {
                float v = acc[i][j][r];
                ps += v * as_v[j];
                pd += v * ad_v[j];
                if (grow < N_NODES)
                    Hf8[(size_t)grow * D1 + col0 + wc * 64 + j * 16 + lm] = f32_to_fp8(v);
            }
            #pragma unroll
            for (int off = 1; off < 16; off <<= 1) {
                ps += __shfl_xor(ps, off);
                pd += __shfl_xor(pd, off);
            }
            if (lm == 0 && grow < N_NODES) {
                a_src1[grow * HEADS + head] = ps;
                a_dst1[grow * HEADS + head] = pd;
            }
        }
    }
}

// ---------------- CSR scan phase 1 ------------------------------------------
__global__ __launch_bounds__(1024) void k_scan1(const int* __restrict__ deg,
                                                int* __restrict__ offsets,
                                                int* __restrict__ bsum) {
    __shared__ int wsum[16];
    int tid = threadIdx.x, lane = tid & 63, wid = tid >> 6;
    int i = blockIdx.x * 1024 + tid;
    int v = (i < N_NODES) ? deg[i] : 0;
    int x = v;
    #pragma unroll
    for (int off = 1; off < 64; off <<= 1) {
        int t = __shfl_up(x, off);
        if (lane >= off) x += t;
    }
    if (lane == 63) wsum[wid] = x;
    __syncthreads();
    if (wid == 0) {
        int s = (lane < 16) ? wsum[lane] : 0;
        #pragma unroll
        for (int off = 1; off < 16; off <<= 1) {
            int t = __shfl_up(s, off);
            if (lane >= off) s += t;
        }
        if (lane < 16) wsum[lane] = s;
    }
    __syncthreads();
    int wbase = wid ? wsum[wid - 1] : 0;
    if (i < N_NODES) offsets[i] = wbase + x - v;
    if (tid == 1023) bsum[blockIdx.x] = wsum[15];
}

// ---------------- scan phase 2+3 fused ---------------------------------------
__global__ __launch_bounds__(256) void k_scan3(int* __restrict__ offsets,
                                               const int* __restrict__ bsum,
                                               int* __restrict__ cursor) {
    __shared__ int bpre_s[64];
    int tid = threadIdx.x;
    const int nb = (N_NODES + 1023) / 1024;   // 49
    if (tid < 64) {
        int v = (tid < nb) ? bsum[tid] : 0;
        int x = v;
        #pragma unroll
        for (int off = 1; off < 64; off <<= 1) {
            int t = __shfl_up(x, off);
            if (tid >= off) x += t;
        }
        bpre_s[tid] = x - v;
        if (blockIdx.x == 0 && tid == nb - 1) offsets[N_NODES] = x;
    }
    __syncthreads();
    int i = blockIdx.x * 256 + tid;
    if (i < N_NODES) {
        int o = offsets[i] + bpre_s[i >> 10];
        offsets[i] = o;
        cursor[i] = o;
    }
}

// ---------------- scatter + fused layer-1 edge weights ----------------------
__global__ void k_scatter(const int* __restrict__ esrc, const int* __restrict__ edst,
                          const float* __restrict__ a_src, const float* __restrict__ a_dst,
                          int* __restrict__ cursor, int* __restrict__ csr,
                          float* __restrict__ w1) {
    int e = blockIdx.x * blockDim.x + threadIdx.x;
    if (e >= N_EDGES) return;
    int s = esrc[e], d = edst[e];
    int pos = atomicAdd(&cursor[d], 1);
    csr[pos] = s;
    float4 s0 = *(const float4*)&a_src[s * HEADS];
    float4 s1 = *(const float4*)&a_src[s * HEADS + 4];
    float4 d0 = *(const float4*)&a_dst[d * HEADS];
    float4 d1 = *(const float4*)&a_dst[d * HEADS + 4];
    float ev[8] = {s0.x + d0.x, s0.y + d0.y, s0.z + d0.z, s0.w + d0.w,
                   s1.x + d1.x, s1.y + d1.y, s1.z + d1.z, s1.w + d1.w};
    float w[8];
    #pragma unroll
    for (int h = 0; h < 8; ++h) {
        float v = ev[h] > 0.f ? ev[h] : NEG_SLOPE * ev[h];
        w[h] = __expf(v);
    }
    *(float4*)&w1[(size_t)pos * 8]     = make_float4(w[0], w[1], w[2], w[3]);
    *(float4*)&w1[(size_t)pos * 8 + 4] = make_float4(w[4], w[5], w[6], w[7]);
}

// ---------------- layer-1 aggregation: pair-edge 1KB gathers (R13 form) -----
__global__ __launch_bounds__(256) void k_agg1(const unsigned char* __restrict__ Hf8,
                                              const float* __restrict__ a_src,
                                              const float* __restrict__ a_dst,
                                              const float* __restrict__ w1,
                                              const int* __restrict__ offsets,
                                              const int* __restrict__ csr,
                                              const float* __restrict__ b1,
                                              __bf16* __restrict__ OUT) {
    int wave = (blockIdx.x * blockDim.x + threadIdx.x) >> 6;
    int lane = threadIdx.x & 63;
    if (wave >= N_NODES) return;
    int d = wave;
    int half = lane >> 5;      // edge parity this lane handles
    int l32 = lane & 31;
    int chb = l32 * 16;        // 16 channels per lane
    int head = l32 >> 2;
    float o[16];
    #pragma unroll
    for (int j = 0; j < 16; ++j) o[j] = 0.f;
    float lsum = 0.f;
    if (half == 0) {           // self-loop handled once
        float es = a_src[d * HEADS + head] + a_dst[d * HEADS + head];
        es = es > 0.f ? es : NEG_SLOPE * es;
        float wself = __expf(es);
        uint4 hu = *(const uint4*)&Hf8[(size_t)d * D1 + chb];
        float hv[16];
        fp8x16_to_f32(hu, hv);
        lsum = wself;
        #pragma unroll
        for (int j = 0; j < 16; ++j) o[j] = wself * hv[j];
    }
    int beg = offsets[d], end = offsets[d + 1];
    int idx = beg;
    for (; idx + 4 <= end; idx += 4) {       // 4 edges / iter, 2 gathers
        int eA = idx + half, eB = idx + 2 + half;
        int sA = csr[eA], sB = csr[eB];
        float wA = w1[(size_t)eA * 8 + head];
        float wB = w1[(size_t)eB * 8 + head];
        uint4 uA = *(const uint4*)&Hf8[(size_t)sA * D1 + chb];
        uint4 uB = *(const uint4*)&Hf8[(size_t)sB * D1 + chb];
        float fA[16], fB[16];
        fp8x16_to_f32(uA, fA);
        fp8x16_to_f32(uB, fB);
        lsum += wA + wB;
        #pragma unroll
        for (int j = 0; j < 16; ++j) o[j] += wA * fA[j] + wB * fB[j];
    }
    for (; idx < end; idx += 2) {            // tail (validity-masked)
        int e = idx + half;
        bool valid = e < end;
        int s = valid ? csr[e] : csr[idx];
        float w = valid ? w1[(size_t)e * 8 + head] : 0.f;
        uint4 u = *(const uint4*)&Hf8[(size_t)s * D1 + chb];
        float f[16];
        fp8x16_to_f32(u, f);
        lsum += w;
        #pragma unroll
        for (int j = 0; j < 16; ++j) o[j] += w * f[j];
    }
    // combine edge-parity halves
    #pragma unroll
    for (int j = 0; j < 16; ++j) o[j] += __shfl_xor(o[j], 32);
    lsum += __shfl_xor(lsum, 32);
    if (half == 0) {
        float inv = 1.0f / (lsum + 1e-16f);
        __bf16 r[16];
        #pragma unroll
        for (int j = 0; j < 16; ++j) {
            float v = o[j] * inv + b1[chb + j];
            v = v > 0.f ? v : (__expf(v) - 1.0f);   // ELU (cheap form)
            r[j] = (__bf16)v;
        }
        *(uint4*)&OUT[(size_t)d * D1 + chb]     = *(uint4*)&r[0];
        *(uint4*)&OUT[(size_t)d * D1 + chb + 8] = *(uint4*)&r[8];
    }
}

// ---------------- GEMM2 (MFMA, no LDS) + layer-2 logits, bf16 H2 ------------
__global__ __launch_bounds__(256) void k_gemm2_mfma(const __bf16* __restrict__ A,
                                                    const __bf16* __restrict__ Wt2,
                                                    const float* __restrict__ as2v,
                                                    const float* __restrict__ ad2v,
                                                    __bf16* __restrict__ H2,
                                                    float* __restrict__ a_src2,
                                                    float* __restrict__ a_dst2) {
    int tid = threadIdx.x;
    int wid = tid >> 6, lane = tid & 63;
    int lq = lane >> 4, lm = lane & 15;
    int row0 = blockIdx.x * 64 + wid * 16;
    int arow = row0 + lm;
    const __bf16* ap = A + (size_t)(arow < N_NODES ? arow : 0) * D1;
    f32x4 acc = {};
    #pragma unroll
    for (int k0 = 0; k0 < 16; ++k0) {
        bf16x8 af  = *(const bf16x8*)&ap[k0 * 32 + lq * 8];
        bf16x8 bfr = *(const bf16x8*)&Wt2[lm * D1 + k0 * 32 + lq * 8];
        acc = __builtin_amdgcn_mfma_f32_16x16x32_bf16(af, bfr, acc, 0, 0, 0);
    }
    float as_c = as2v[lm], ad_c = ad2v[lm];
    #pragma unroll
    for (int r = 0; r < 4; ++r) {
        int gr = row0 + lq * 4 + r;
        float v = acc[r];
        if (gr < N_NODES) H2[gr * OUT_CH + lm] = (__bf16)v;
        float ps = v * as_c, pd = v * ad_c;
        #pragma unroll
        for (int off = 1; off < 16; off <<= 1) {
            ps += __shfl_xor(ps, off);
            pd += __shfl_xor(pd, off);
        }
        if (lm == 0 && gr < N_NODES) { a_src2[gr] = ps; a_dst2[gr] = pd; }
    }
}

// ---------------- layer-2 aggregation + inline weights + log_softmax --------
__global__ __launch_bounds__(256) void k_agg2(const __bf16* __restrict__ H2,
                                              const float* __restrict__ a_src,
                                              const float* __restrict__ a_dst,
                                              const int* __restrict__ offsets,
                                              const int* __restrict__ csr,
                                              const float* __restrict__ b2,
                                              float* __restrict__ OUT) {
    int wave = (blockIdx.x * blockDim.x + threadIdx.x) >> 6;
    int lane = threadIdx.x & 63;
    if (wave >= N_NODES) return;
    int d = wave;
    int g = lane >> 4, c = lane & 15;
    float ad = a_dst[d];
    float es = a_src[d] + ad;
    es = es > 0.f ? es : NEG_SLOPE * es;
    float wself = __expf(es);
    int beg = offsets[d], end = offsets[d + 1];
    float o = 0.f, lsum = 0.f;
    if (g == 0) {
        o = wself * (float)H2[d * OUT_CH + c];
        lsum = wself;
    }
    for (int idx = beg + g; idx < end; idx += 4) {
        int s = csr[idx];
        float e = a_src[s] + ad;
        e = e > 0.f ? e : NEG_SLOPE * e;
        float w = __expf(e);
        lsum += w;
        o += w * (float)H2[s * OUT_CH + c];
    }
    o += __shfl_xor(o, 16);  o += __shfl_xor(o, 32);
    lsum += __shfl_xor(lsum, 16);  lsum += __shfl_xor(lsum, 32);
    float v = o / (lsum + 1e-16f) + b2[c];
    float mx = v;
    #pragma unroll
    for (int off = 1; off < 16; off <<= 1) mx = fmaxf(mx, __shfl_xor(mx, off));
    float se = __expf(v - mx);
    #pragma unroll
    for (int off = 1; off < 16; off <<= 1) se += __shfl_xor(se, off);
    float res = v - mx - logf(se);
    if (lane < 16) OUT[d * OUT_CH + lane] = res;
}

// ---------------- launcher --------------------------------------------------
extern "C" void kernel_launch(void* const* d_in, const int* in_sizes, int n_in,
                              void* d_out, int out_size, void* d_ws, size_t ws_size,
                              hipStream_t stream) {
    const float* x        = (const float*)d_in[0];
    const int*   ei       = (const int*)d_in[1];
    const float* W1       = (const float*)d_in[2];
    const float* att_src1 = (const float*)d_in[3];
    const float* att_dst1 = (const float*)d_in[4];
    const float* b1       = (const float*)d_in[5];
    const float* W2       = (const float*)d_in[6];
    const float* att_src2 = (const float*)d_in[7];
    const float* att_dst2 = (const float*)d_in[8];
    const float* b2       = (const float*)d_in[9];
    float* out = (float*)d_out;

    const int* esrc = ei;
    const int* edst = ei + N_EDGES;

    char* ws = (char*)d_ws;
    size_t off = 0;
    auto alloc = [&](size_t bytes) { char* p = ws + off; off = (off + bytes + 255) & ~(size_t)255; return p; };
    unsigned char* Hf8 = (unsigned char*)alloc((size_t)N_NODES * D1); // 25.6 MB
    __bf16* out1   = (__bf16*)alloc((size_t)N_NODES * D1 * 2);        // 51.2 MB
    __bf16* Xb     = (__bf16*)alloc((size_t)N_NODES * IN_CH * 2);     // 25.6 MB
    __bf16* Wt     = (__bf16*)alloc((size_t)D1 * IN_CH * 2);          // (also absorbs gemm1 overread)
    __bf16* Wt2    = (__bf16*)alloc((size_t)D1 * OUT_CH * 2);
    float* a_src1  = (float*)alloc((size_t)N_NODES * HEADS * 4);
    float* a_dst1  = (float*)alloc((size_t)N_NODES * HEADS * 4);
    float* w1      = (float*)alloc((size_t)N_EDGES * HEADS * 4);      // 16 MB
    __bf16* h2     = (__bf16*)alloc((size_t)N_NODES * OUT_CH * 2);    // 1.6 MB
    float* a_src2  = (float*)alloc((size_t)N_NODES * 4);
    float* a_dst2  = (float*)alloc((size_t)N_NODES * 4);
    int*   deg     = (int*)alloc((size_t)N_NODES * 4);
    int*   offsets = (int*)alloc((size_t)(N_NODES + 1) * 4);
    int*   cursor  = (int*)alloc((size_t)N_NODES * 4);
    int*   csr     = (int*)alloc((size_t)N_EDGES * 4);
    int*   bsum    = (int*)alloc(64 * 4);
    (void)ws_size;

    // 0. zero deg, then prep (X/W converts + histogram)
    hipMemsetAsync(deg, 0, (size_t)N_NODES * 4, stream);
    k_prep<<<512, 256, 0, stream>>>(x, W1, W2, edst, Xb, Wt, Wt2, deg);
    // 1. GEMM1 (MFMA, dbuf async LDS staging) + att1 logits, fp8 H out
    dim3 g1((N_NODES + 127) / 128, D1 / 128);
    k_gemm1_mfma<<<g1, 256, 0, stream>>>(Xb, Wt, att_src1, att_dst1, Hf8, a_src1, a_dst1);
    // 2. CSR build
    int nb = (N_NODES + 1023) / 1024;
    k_scan1<<<nb, 1024, 0, stream>>>(deg, offsets, bsum);
    k_scan3<<<(N_NODES + 255) / 256, 256, 0, stream>>>(offsets, bsum, cursor);
    k_scatter<<<(N_EDGES + 255) / 256, 256, 0, stream>>>(esrc, edst, a_src1, a_dst1,
                                                         cursor, csr, w1);
    // 3. layer-1 aggregation (+bias+ELU), pair-edge fp8 gather
    k_agg1<<<(N_NODES * 64 + 255) / 256, 256, 0, stream>>>(Hf8, a_src1, a_dst1, w1, offsets, csr, b1, out1);
    // 4. GEMM2 (MFMA) + layer-2 logits, bf16 H2
    k_gemm2_mfma<<<(N_NODES + 63) / 64, 256, 0, stream>>>(out1, Wt2, att_src2, att_dst2, h2, a_src2, a_dst2);
    // 5. layer-2 aggregation (inline weights) + log_softmax
    k_agg2<<<(N_NODES * 64 + 255) / 256, 256, 0, stream>>>(h2, a_src2, a_dst2, offsets, csr, b2, out);
}

// Round 16
// 287.840 us; speedup vs baseline: 1.0434x; 1.0202x over previous
//
#include <hip/hip_runtime.h>
#include <math.h>

#define N_NODES 50000
#define N_EDGES 500000
#define IN_CH 256
#define D1 512          // HEADS*HID
#define HEADS 8
#define HID 64
#define OUT_CH 16
#define NEG_SLOPE 0.2f

typedef __bf16 bf16x8 __attribute__((ext_vector_type(8)));
typedef float f32x4 __attribute__((ext_vector_type(4)));
typedef float f32x2 __attribute__((ext_vector_type(2)));

// convert 8 packed fp8 e4m3 (uint2) -> 8 floats via HW v_cvt_pk_f32_fp8
__device__ inline void fp8x8_to_f32(uint2 u, float* f) {
    f32x2 p0 = __builtin_amdgcn_cvt_pk_f32_fp8(u.x, false);
    f32x2 p1 = __builtin_amdgcn_cvt_pk_f32_fp8(u.x, true);
    f32x2 p2 = __builtin_amdgcn_cvt_pk_f32_fp8(u.y, false);
    f32x2 p3 = __builtin_amdgcn_cvt_pk_f32_fp8(u.y, true);
    f[0] = p0.x; f[1] = p0.y; f[2] = p1.x; f[3] = p1.y;
    f[4] = p2.x; f[5] = p2.y; f[6] = p3.x; f[7] = p3.y;
}

__device__ inline void fp8x16_to_f32(uint4 u, float* f) {
    fp8x8_to_f32(make_uint2(u.x, u.y), f);
    fp8x8_to_f32(make_uint2(u.z, u.w), f + 8);
}

__device__ inline unsigned char f32_to_fp8(float v) {
    return (unsigned char)(__builtin_amdgcn_cvt_pk_fp8_f32(v, v, 0, false) & 0xff);
}

// async global->LDS, 16B per lane; LDS dest = wave-uniform base + lane*16
__device__ inline void gl_lds16(const __bf16* g, __bf16* l) {
    __builtin_amdgcn_global_load_lds(
        (const __attribute__((address_space(1))) unsigned int*)g,
        (__attribute__((address_space(3))) unsigned int*)l,
        16, 0, 0);
}

// ---------------- prep: X/W converts + edge histogram (deg pre-zeroed) ------
__global__ __launch_bounds__(256) void k_prep(const float* __restrict__ X,
                                              const float* __restrict__ W1,
                                              const float* __restrict__ W2,
                                              const int* __restrict__ edst,
                                              __bf16* __restrict__ Xb,
                                              __bf16* __restrict__ Wt,
                                              __bf16* __restrict__ Wt2,
                                              int* __restrict__ deg) {
    int t = blockIdx.x * 256 + threadIdx.x;
    int nthr = gridDim.x * 256;
    for (int i = t; i < N_NODES * IN_CH / 8; i += nthr) {
        size_t base = (size_t)i * 8;
        float4 v0 = *(const float4*)&X[base];
        float4 v1 = *(const float4*)&X[base + 4];
        __bf16 o[8] = {(__bf16)v0.x, (__bf16)v0.y, (__bf16)v0.z, (__bf16)v0.w,
                       (__bf16)v1.x, (__bf16)v1.y, (__bf16)v1.z, (__bf16)v1.w};
        *(uint4*)&Xb[base] = *(uint4*)o;
    }
    for (int i = t; i < D1 * IN_CH; i += nthr) {
        int n = i >> 8, k = i & 255;
        Wt[i] = (__bf16)W1[k * D1 + n];
    }
    for (int i = t; i < D1 * OUT_CH; i += nthr) {
        int n = i >> 9, k = i & 511;
        Wt2[i] = (__bf16)W2[k * OUT_CH + n];
    }
    for (int i = t; i < N_EDGES; i += nthr) atomicAdd(&deg[edst[i]], 1);
}

// ---------------- GEMM1 (MFMA, BK=64 swizzled global_load_lds) + att1 -------
// 4 K-iterations (8 barriers vs 16), 8 async loads in flight per wave per
// iteration. LDS layout XOR-swizzled: chunk c of row r stored at position
// c^(r&7) -- only the GLOBAL source is permuted (LDS dest must stay
// wave-uniform + lane*16), and fragment reads land on 8 distinct bank
// groups (2-way aliasing = free) instead of 16-way.
__global__ __launch_bounds__(256) void k_gemm1_mfma(const __bf16* __restrict__ Xb,
                                                    const __bf16* __restrict__ Wt,
                                                    const float* __restrict__ att_src,
                                                    const float* __restrict__ att_dst,
                                                    unsigned char* __restrict__ Hf8,
                                                    float* __restrict__ a_src1,
                                                    float* __restrict__ a_dst1) {
    __shared__ __align__(16) __bf16 As[128 * 64];   // 16 KB, row stride 64
    __shared__ __align__(16) __bf16 Bs[128 * 64];   // 16 KB
    int tid = threadIdx.x;
    int wid = tid >> 6, lane = tid & 63;
    int wr = wid >> 1, wc = wid & 1;           // 2x2 waves of 64x64
    int row0 = blockIdx.x * 128;
    int col0 = blockIdx.y * 128;
    int lq = lane >> 4;
    int lm = lane & 15;
    int sw = lm & 7;                           // per-lane read swizzle
    // staging coords: 4 chunks each of A and B per thread
    int r_st[4], g_st[4];
    #pragma unroll
    for (int it = 0; it < 4; ++it) {
        int idx = tid + it * 256;              // 0..1023
        int r = idx >> 3;                      // row 0..127
        int p = idx & 7;                       // stored chunk position
        r_st[it] = r;
        g_st[it] = (p ^ (r & 7)) * 8;          // source col within 64-wide tile
    }
    f32x4 acc[4][4] = {};
    for (int kt = 0; kt < IN_CH / 64; ++kt) {
        int k0 = kt * 64;
        #pragma unroll
        for (int it = 0; it < 4; ++it) {
            int idx = tid + it * 256;
            gl_lds16(&Xb[(size_t)(row0 + r_st[it]) * IN_CH + k0 + g_st[it]], &As[idx * 8]);
            gl_lds16(&Wt[(size_t)(col0 + r_st[it]) * IN_CH + k0 + g_st[it]], &Bs[idx * 8]);
        }
        __syncthreads();   // drains vmcnt: tile visible
        #pragma unroll
        for (int kt2 = 0; kt2 < 2; ++kt2) {
            bf16x8 af[4], bfr[4];
            #pragma unroll
            for (int i = 0; i < 4; ++i)
                af[i]  = *(bf16x8*)&As[(wr * 64 + i * 16 + lm) * 64 + (((kt2 * 4 + lq) ^ sw) * 8)];
            #pragma unroll
            for (int j = 0; j < 4; ++j)
                bfr[j] = *(bf16x8*)&Bs[(wc * 64 + j * 16 + lm) * 64 + (((kt2 * 4 + lq) ^ sw) * 8)];
            #pragma unroll
            for (int i = 0; i < 4; ++i)
                #pragma unroll
                for (int j = 0; j < 4; ++j)
                    acc[i][j] = __builtin_amdgcn_mfma_f32_16x16x32_bf16(af[i], bfr[j], acc[i][j], 0, 0, 0);
        }
        __syncthreads();   // all reads done before next overwrite
    }
    // ---- epilogue: fused att logits + fp8 byte stores ----
    int head = blockIdx.y * 2 + wc;
    float as_v[4], ad_v[4];
    #pragma unroll
    for (int j = 0; j < 4; ++j) {
        as_v[j] = att_src[head * HID + j * 16 + lm];
        ad_v[j] = att_dst[head * HID + j * 16 + lm];
    }
    #pragma unroll
    for (int i = 0; i < 4; ++i) {
        int rbase = row0 + wr * 64 + i * 16 + lq * 4;
        #pragma unroll
        for (int r = 0; r < 4; ++r) {
            int grow = rbase + r;
            float ps = 0.f, pd = 0.f;
            #pragma unroll
            for (int j = 0; j < 4; ++j) {
                float v = acc[i][j][r];
                ps += v * as_v[j];
                pd += v * ad_v[j];
                if (grow < N_NODES)
                    Hf8[(size_t)grow * D1 + col0 + wc * 64 + j * 16 + lm] = f32_to_fp8(v);
            }
            #pragma unroll
            for (int off = 1; off < 16; off <<= 1) {
                ps += __shfl_xor(ps, off);
                pd += __shfl_xor(pd, off);
            }
            if (lm == 0 && grow < N_NODES) {
                a_src1[grow * HEADS + head] = ps;
                a_dst1[grow * HEADS + head] = pd;
            }
        }
    }
}

// ---------------- CSR scan phase 1 ------------------------------------------
__global__ __launch_bounds__(1024) void k_scan1(const int* __restrict__ deg,
                                                int* __restrict__ offsets,
                                                int* __restrict__ bsum) {
    __shared__ int wsum[16];
    int tid = threadIdx.x, lane = tid & 63, wid = tid >> 6;
    int i = blockIdx.x * 1024 + tid;
    int v = (i < N_NODES) ? deg[i] : 0;
    int x = v;
    #pragma unroll
    for (int off = 1; off < 64; off <<= 1) {
        int t = __shfl_up(x, off);
        if (lane >= off) x += t;
    }
    if (lane == 63) wsum[wid] = x;
    __syncthreads();
    if (wid == 0) {
        int s = (lane < 16) ? wsum[lane] : 0;
        #pragma unroll
        for (int off = 1; off < 16; off <<= 1) {
            int t = __shfl_up(s, off);
            if (lane >= off) s += t;
        }
        if (lane < 16) wsum[lane] = s;
    }
    __syncthreads();
    int wbase = wid ? wsum[wid - 1] : 0;
    if (i < N_NODES) offsets[i] = wbase + x - v;
    if (tid == 1023) bsum[blockIdx.x] = wsum[15];
}

// ---------------- scan phase 2+3 fused ---------------------------------------
__global__ __launch_bounds__(256) void k_scan3(int* __restrict__ offsets,
                                               const int* __restrict__ bsum,
                                               int* __restrict__ cursor) {
    __shared__ int bpre_s[64];
    int tid = threadIdx.x;
    const int nb = (N_NODES + 1023) / 1024;   // 49
    if (tid < 64) {
        int v = (tid < nb) ? bsum[tid] : 0;
        int x = v;
        #pragma unroll
        for (int off = 1; off < 64; off <<= 1) {
            int t = __shfl_up(x, off);
            if (tid >= off) x += t;
        }
        bpre_s[tid] = x - v;
        if (blockIdx.x == 0 && tid == nb - 1) offsets[N_NODES] = x;
    }
    __syncthreads();
    int i = blockIdx.x * 256 + tid;
    if (i < N_NODES) {
        int o = offsets[i] + bpre_s[i >> 10];
        offsets[i] = o;
        cursor[i] = o;
    }
}

// ---------------- scatter + fused layer-1 edge weights ----------------------
__global__ void k_scatter(const int* __restrict__ esrc, const int* __restrict__ edst,
                          const float* __restrict__ a_src, const float* __restrict__ a_dst,
                          int* __restrict__ cursor, int* __restrict__ csr,
                          float* __restrict__ w1) {
    int e = blockIdx.x * blockDim.x + threadIdx.x;
    if (e >= N_EDGES) return;
    int s = esrc[e], d = edst[e];
    int pos = atomicAdd(&cursor[d], 1);
    csr[pos] = s;
    float4 s0 = *(const float4*)&a_src[s * HEADS];
    float4 s1 = *(const float4*)&a_src[s * HEADS + 4];
    float4 d0 = *(const float4*)&a_dst[d * HEADS];
    float4 d1 = *(const float4*)&a_dst[d * HEADS + 4];
    float ev[8] = {s0.x + d0.x, s0.y + d0.y, s0.z + d0.z, s0.w + d0.w,
                   s1.x + d1.x, s1.y + d1.y, s1.z + d1.z, s1.w + d1.w};
    float w[8];
    #pragma unroll
    for (int h = 0; h < 8; ++h) {
        float v = ev[h] > 0.f ? ev[h] : NEG_SLOPE * ev[h];
        w[h] = __expf(v);
    }
    *(float4*)&w1[(size_t)pos * 8]     = make_float4(w[0], w[1], w[2], w[3]);
    *(float4*)&w1[(size_t)pos * 8 + 4] = make_float4(w[4], w[5], w[6], w[7]);
}

// ---------------- layer-1 aggregation: pair-edge 1KB gathers (R13 form) -----
__global__ __launch_bounds__(256) void k_agg1(const unsigned char* __restrict__ Hf8,
                                              const float* __restrict__ a_src,
                                              const float* __restrict__ a_dst,
                                              const float* __restrict__ w1,
                                              const int* __restrict__ offsets,
                                              const int* __restrict__ csr,
                                              const float* __restrict__ b1,
                                              __bf16* __restrict__ OUT) {
    int wave = (blockIdx.x * blockDim.x + threadIdx.x) >> 6;
    int lane = threadIdx.x & 63;
    if (wave >= N_NODES) return;
    int d = wave;
    int half = lane >> 5;      // edge parity this lane handles
    int l32 = lane & 31;
    int chb = l32 * 16;        // 16 channels per lane
    int head = l32 >> 2;
    float o[16];
    #pragma unroll
    for (int j = 0; j < 16; ++j) o[j] = 0.f;
    float lsum = 0.f;
    if (half == 0) {           // self-loop handled once
        float es = a_src[d * HEADS + head] + a_dst[d * HEADS + head];
        es = es > 0.f ? es : NEG_SLOPE * es;
        float wself = __expf(es);
        uint4 hu = *(const uint4*)&Hf8[(size_t)d * D1 + chb];
        float hv[16];
        fp8x16_to_f32(hu, hv);
        lsum = wself;
        #pragma unroll
        for (int j = 0; j < 16; ++j) o[j] = wself * hv[j];
    }
    int beg = offsets[d], end = offsets[d + 1];
    int idx = beg;
    for (; idx + 4 <= end; idx += 4) {       // 4 edges / iter, 2 gathers
        int eA = idx + half, eB = idx + 2 + half;
        int sA = csr[eA], sB = csr[eB];
        float wA = w1[(size_t)eA * 8 + head];
        float wB = w1[(size_t)eB * 8 + head];
        uint4 uA = *(const uint4*)&Hf8[(size_t)sA * D1 + chb];
        uint4 uB = *(const uint4*)&Hf8[(size_t)sB * D1 + chb];
        float fA[16], fB[16];
        fp8x16_to_f32(uA, fA);
        fp8x16_to_f32(uB, fB);
        lsum += wA + wB;
        #pragma unroll
        for (int j = 0; j < 16; ++j) o[j] += wA * fA[j] + wB * fB[j];
    }
    for (; idx < end; idx += 2) {            // tail (validity-masked)
        int e = idx + half;
        bool valid = e < end;
        int s = valid ? csr[e] : csr[idx];
        float w = valid ? w1[(size_t)e * 8 + head] : 0.f;
        uint4 u = *(const uint4*)&Hf8[(size_t)s * D1 + chb];
        float f[16];
        fp8x16_to_f32(u, f);
        lsum += w;
        #pragma unroll
        for (int j = 0; j < 16; ++j) o[j] += w * f[j];
    }
    // combine edge-parity halves
    #pragma unroll
    for (int j = 0; j < 16; ++j) o[j] += __shfl_xor(o[j], 32);
    lsum += __shfl_xor(lsum, 32);
    if (half == 0) {
        float inv = 1.0f / (lsum + 1e-16f);
        __bf16 r[16];
        #pragma unroll
        for (int j = 0; j < 16; ++j) {
            float v = o[j] * inv + b1[chb + j];
            v = v > 0.f ? v : (__expf(v) - 1.0f);   // ELU (cheap form)
            r[j] = (__bf16)v;
        }
        *(uint4*)&OUT[(size_t)d * D1 + chb]     = *(uint4*)&r[0];
        *(uint4*)&OUT[(size_t)d * D1 + chb + 8] = *(uint4*)&r[8];
    }
}

// ---------------- GEMM2 (MFMA, no LDS) + layer-2 logits, bf16 H2 ------------
__global__ __launch_bounds__(256) void k_gemm2_mfma(const __bf16* __restrict__ A,
                                                    const __bf16* __restrict__ Wt2,
                                                    const float* __restrict__ as2v,
                                                    const float* __restrict__ ad2v,
                                                    __bf16* __restrict__ H2,
                                                    float* __restrict__ a_src2,
                                                    float* __restrict__ a_dst2) {
    int tid = threadIdx.x;
    int wid = tid >> 6, lane = tid & 63;
    int lq = lane >> 4, lm = lane & 15;
    int row0 = blockIdx.x * 64 + wid * 16;
    int arow = row0 + lm;
    const __bf16* ap = A + (size_t)(arow < N_NODES ? arow : 0) * D1;
    f32x4 acc = {};
    #pragma unroll
    for (int k0 = 0; k0 < 16; ++k0) {
        bf16x8 af  = *(const bf16x8*)&ap[k0 * 32 + lq * 8];
        bf16x8 bfr = *(const bf16x8*)&Wt2[lm * D1 + k0 * 32 + lq * 8];
        acc = __builtin_amdgcn_mfma_f32_16x16x32_bf16(af, bfr, acc, 0, 0, 0);
    }
    float as_c = as2v[lm], ad_c = ad2v[lm];
    #pragma unroll
    for (int r = 0; r < 4; ++r) {
        int gr = row0 + lq * 4 + r;
        float v = acc[r];
        if (gr < N_NODES) H2[gr * OUT_CH + lm] = (__bf16)v;
        float ps = v * as_c, pd = v * ad_c;
        #pragma unroll
        for (int off = 1; off < 16; off <<= 1) {
            ps += __shfl_xor(ps, off);
            pd += __shfl_xor(pd, off);
        }
        if (lm == 0 && gr < N_NODES) { a_src2[gr] = ps; a_dst2[gr] = pd; }
    }
}

// ---------------- layer-2 aggregation + inline weights + log_softmax --------
__global__ __launch_bounds__(256) void k_agg2(const __bf16* __restrict__ H2,
                                              const float* __restrict__ a_src,
                                              const float* __restrict__ a_dst,
                                              const int* __restrict__ offsets,
                                              const int* __restrict__ csr,
                                              const float* __restrict__ b2,
                                              float* __restrict__ OUT) {
    int wave = (blockIdx.x * blockDim.x + threadIdx.x) >> 6;
    int lane = threadIdx.x & 63;
    if (wave >= N_NODES) return;
    int d = wave;
    int g = lane >> 4, c = lane & 15;
    float ad = a_dst[d];
    float es = a_src[d] + ad;
    es = es > 0.f ? es : NEG_SLOPE * es;
    float wself = __expf(es);
    int beg = offsets[d], end = offsets[d + 1];
    float o = 0.f, lsum = 0.f;
    if (g == 0) {
        o = wself * (float)H2[d * OUT_CH + c];
        lsum = wself;
    }
    for (int idx = beg + g; idx < end; idx += 4) {
        int s = csr[idx];
        float e = a_src[s] + ad;
        e = e > 0.f ? e : NEG_SLOPE * e;
        float w = __expf(e);
        lsum += w;
        o += w * (float)H2[s * OUT_CH + c];
    }
    o += __shfl_xor(o, 16);  o += __shfl_xor(o, 32);
    lsum += __shfl_xor(lsum, 16);  lsum += __shfl_xor(lsum, 32);
    float v = o / (lsum + 1e-16f) + b2[c];
    float mx = v;
    #pragma unroll
    for (int off = 1; off < 16; off <<= 1) mx = fmaxf(mx, __shfl_xor(mx, off));
    float se = __expf(v - mx);
    #pragma unroll
    for (int off = 1; off < 16; off <<= 1) se += __shfl_xor(se, off);
    float res = v - mx - logf(se);
    if (lane < 16) OUT[d * OUT_CH + lane] = res;
}

// ---------------- launcher --------------------------------------------------
extern "C" void kernel_launch(void* const* d_in, const int* in_sizes, int n_in,
                              void* d_out, int out_size, void* d_ws, size_t ws_size,
                              hipStream_t stream) {
    const float* x        = (const float*)d_in[0];
    const int*   ei       = (const int*)d_in[1];
    const float* W1       = (const float*)d_in[2];
    const float* att_src1 = (const float*)d_in[3];
    const float* att_dst1 = (const float*)d_in[4];
    const float* b1       = (const float*)d_in[5];
    const float* W2       = (const float*)d_in[6];
    const float* att_src2 = (const float*)d_in[7];
    const float* att_dst2 = (const float*)d_in[8];
    const float* b2       = (const float*)d_in[9];
    float* out = (float*)d_out;

    const int* esrc = ei;
    const int* edst = ei + N_EDGES;

    char* ws = (char*)d_ws;
    size_t off = 0;
    auto alloc = [&](size_t bytes) { char* p = ws + off; off = (off + bytes + 255) & ~(size_t)255; return p; };
    unsigned char* Hf8 = (unsigned char*)alloc((size_t)N_NODES * D1); // 25.6 MB
    __bf16* out1   = (__bf16*)alloc((size_t)N_NODES * D1 * 2);        // 51.2 MB
    __bf16* Xb     = (__bf16*)alloc((size_t)N_NODES * IN_CH * 2);     // 25.6 MB
    __bf16* Wt     = (__bf16*)alloc((size_t)D1 * IN_CH * 2);          // (also absorbs gemm1 overread)
    __bf16* Wt2    = (__bf16*)alloc((size_t)D1 * OUT_CH * 2);
    float* a_src1  = (float*)alloc((size_t)N_NODES * HEADS * 4);
    float* a_dst1  = (float*)alloc((size_t)N_NODES * HEADS * 4);
    float* w1      = (float*)alloc((size_t)N_EDGES * HEADS * 4);      // 16 MB
    __bf16* h2     = (__bf16*)alloc((size_t)N_NODES * OUT_CH * 2);    // 1.6 MB
    float* a_src2  = (float*)alloc((size_t)N_NODES * 4);
    float* a_dst2  = (float*)alloc((size_t)N_NODES * 4);
    int*   deg     = (int*)alloc((size_t)N_NODES * 4);
    int*   offsets = (int*)alloc((size_t)(N_NODES + 1) * 4);
    int*   cursor  = (int*)alloc((size_t)N_NODES * 4);
    int*   csr     = (int*)alloc((size_t)N_EDGES * 4);
    int*   bsum    = (int*)alloc(64 * 4);
    (void)ws_size;

    // 0. zero deg, then prep (X/W converts + histogram)
    hipMemsetAsync(deg, 0, (size_t)N_NODES * 4, stream);
    k_prep<<<512, 256, 0, stream>>>(x, W1, W2, edst, Xb, Wt, Wt2, deg);
    // 1. GEMM1 (MFMA, BK=64 swizzled async staging) + att1 logits, fp8 H out
    dim3 g1((N_NODES + 127) / 128, D1 / 128);
    k_gemm1_mfma<<<g1, 256, 0, stream>>>(Xb, Wt, att_src1, att_dst1, Hf8, a_src1, a_dst1);
    // 2. CSR build
    int nb = (N_NODES + 1023) / 1024;
    k_scan1<<<nb, 1024, 0, stream>>>(deg, offsets, bsum);
    k_scan3<<<(N_NODES + 255) / 256, 256, 0, stream>>>(offsets, bsum, cursor);
    k_scatter<<<(N_EDGES + 255) / 256, 256, 0, stream>>>(esrc, edst, a_src1, a_dst1,
                                                         cursor, csr, w1);
    // 3. layer-1 aggregation (+bias+ELU), pair-edge fp8 gather
    k_agg1<<<(N_NODES * 64 + 255) / 256, 256, 0, stream>>>(Hf8, a_src1, a_dst1, w1, offsets, csr, b1, out1);
    // 4. GEMM2 (MFMA) + layer-2 logits, bf16 H2
    k_gemm2_mfma<<<(N_NODES + 63) / 64, 256, 0, stream>>>(out1, Wt2, att_src2, att_dst2, h2, a_src2, a_dst2);
    // 5. layer-2 aggregation (inline weights) + log_softmax
    k_agg2<<<(N_NODES * 64 + 255) / 256, 256, 0, stream>>>(h2, a_src2, a_dst2, offsets, csr, b2, out);
}